// Round 5
// baseline (25273.720 us; speedup 1.0000x reference)
//
#include <hip/hip_runtime.h>
#include <stdint.h>

#define B_   128
#define T_   4096
#define F_   64
#define H0_  77
#define H1_  51
#define H2_  128
#define K0_  141
#define K1_  128
#define K2_  179
// Each unit's dot product is split across 4 lanes (1024 threads/block) so the
// packed weights fit the hard 128-VGPR cap (16 waves/block -> 4 waves/SIMD).
// Per-lane unrolled pair count is uniform 24; per-layer part bases are EVEN
// (18/16/24) so every lane's z slice is 16B-aligned -> float4 LDS loads.
#define NPL4 24
#define ZROW 192           // floats per z row (zero-padded)
#define ZBUF 576           // floats per z buffer (3 rows); double-buffered

typedef _Float16 half2_t __attribute__((ext_vector_type(2)));

__device__ inline float bf2f(unsigned short v) {
    unsigned u = ((unsigned)v) << 16;
    return __builtin_bit_cast(float, u);
}
__device__ inline unsigned short f2bf(float f) {
    unsigned u = __builtin_bit_cast(unsigned, f);
    unsigned r = (u + 0x7FFFu + ((u >> 16) & 1u)) >> 16;   // RNE, finite values
    return (unsigned short)r;
}
__device__ inline uint32_t packh2(float a, float b) {
    half2_t h; h.x = (_Float16)a; h.y = (_Float16)b;
    return __builtin_bit_cast(uint32_t, h);
}
__device__ inline half2_t u2h(uint32_t u) { return __builtin_bit_cast(half2_t, u); }

// dt: 0 = fp32, 1 = bf16, 2 = fp16
__device__ inline float ldany(const void* p, size_t i, int dt) {
    if (dt == 0) return ((const float*)p)[i];
    if (dt == 1) return bf2f(((const unsigned short*)p)[i]);
    return (float)((const _Float16*)p)[i];
}
__device__ inline void stout(void* p, size_t i, float v, int dt) {
    if (dt == 0)      ((float*)p)[i] = v;
    else if (dt == 1) ((unsigned short*)p)[i] = f2bf(v);
    else              ((_Float16*)p)[i] = (_Float16)v;
}

__device__ inline float sigm_f(float x) { return 1.0f / (1.0f + __expf(-x)); }
__device__ inline float tanh_f(float x) { return 2.0f / (1.0f + __expf(-2.0f * x)) - 1.0f; }

// quad-perm DPP butterfly add (pure VALU; avoids ds_bpermute LDS traffic).
// CTRL must be a compile-time constant (builtin requirement) -> template arg.
// 0xB1 = quad_perm(1,0,3,2) -> lane^1 ; 0x4E = quad_perm(2,3,0,1) -> lane^2
template <int CTRL>
__device__ inline float dpp_add(float x) {
    int v = __builtin_amdgcn_update_dpp(0, __builtin_bit_cast(int, x),
                                        CTRL, 0xF, 0xF, true);
    return x + __builtin_bit_cast(float, v);
}
__device__ inline float quad_reduce(float x) {
    x = dpp_add<0xB1>(x);
    x = dpp_add<0x4E>(x);
    return x;
}

struct Params { const void* in[29]; };

// 1024 threads: unit = tid>>2 (0..255 = [L0|L1|L2] state order), part = tid&3.
// Software pipeline: tick s computes L0:h0(s+1), L1:h1(s), L2:h2(s-1) in
// parallel; z block double-buffered (read buf[s&1], write buf[s&1^1]);
// ONE barrier per tick. Bias added ONCE after the quad reduction.
__global__ __launch_bounds__(1024, 4)
void liquid_cfc_kernel(Params p, void* __restrict__ outp) {
    const int tid  = threadIdx.x;
    const int b    = blockIdx.x;
    const int unit = tid >> 2;
    const int part = tid & 3;

    int lay, u, k, nph, pbase, zbase, smin;
    if (unit < H0_) {
        lay = 0; u = unit;       k = K0_; zbase = 0;        smin = 0;
        pbase = part * 18; nph = (part == 3) ? 17 : 18;     // 71 pairs
    } else if (unit < H0_ + H1_) {
        lay = 1; u = unit - H0_; k = K1_; zbase = ZROW;     smin = 1;
        pbase = part * 16; nph = 16;                        // 64 pairs
    } else {
        lay = 2; u = unit - 128; k = K2_; zbase = 2 * ZROW; smin = 2;
        pbase = part * 24; nph = (part == 3) ? 18 : 24;     // 90 pairs
    }
    const int smax = smin + T_ - 1;

    const void* xp  = p.in[0];
    const void* h0p = p.in[1];
    // dict order per layer: m, W1, W2, Wa, Wb, b1, b2, ba, bb
    const void* Mp  = p.in[2 + 9 * lay + 0];
    const void* W1p = p.in[2 + 9 * lay + 1];
    const void* W2p = p.in[2 + 9 * lay + 2];
    const void* Wap = p.in[2 + 9 * lay + 3];
    const void* Wbp = p.in[2 + 9 * lay + 4];
    const void* B1p = p.in[2 + 9 * lay + 5];
    const void* B2p = p.in[2 + 9 * lay + 6];
    const void* Bap = p.in[2 + 9 * lay + 7];
    const void* Bbp = p.in[2 + 9 * lay + 8];

    // dtype probe on mask m_0 (values exactly 0.0/1.0)
    int dt;
    {
        const unsigned short* q = (const unsigned short*)p.in[2];
        bool anyf16 = false, lowNZ = false;
        for (int i = 0; i < 64; ++i) {
            unsigned short v = q[i];
            if (v == 0x3C00) anyf16 = true;
            if ((i & 1) == 0 && v != 0) lowNZ = true;
        }
        dt = anyf16 ? 2 : (lowNZ ? 1 : 0);
    }

    // one-time: load + mask + fold (Wa+Wb); this lane holds pairs
    // [pbase, pbase+nph) of its unit's row (zero-padded to NPL4).
    // 3 x 24 u32 = 72 VGPRs -> fits the 128-reg cap, truly register-resident.
    const int rowoff = u * k;
    uint32_t wp1[NPL4], wp2[NPL4], wpc[NPL4];
#pragma unroll
    for (int i = 0; i < NPL4; ++i) {
        const int c0 = 2 * (pbase + i), c1 = c0 + 1;
        const bool v0 = (i < nph) && (c0 < k);
        const bool v1 = (i < nph) && (c1 < k);
        float m0 = 0.f, m1 = 0.f, v1a = 0.f, v1b = 0.f, v2a = 0.f, v2b = 0.f,
              vca = 0.f, vcb = 0.f;
        if (v0) {
            m0  = ldany(Mp,  rowoff + c0, dt);
            v1a = ldany(W1p, rowoff + c0, dt);
            v2a = ldany(W2p, rowoff + c0, dt);
            vca = ldany(Wap, rowoff + c0, dt) + ldany(Wbp, rowoff + c0, dt);
        }
        if (v1) {
            m1  = ldany(Mp,  rowoff + c1, dt);
            v1b = ldany(W1p, rowoff + c1, dt);
            v2b = ldany(W2p, rowoff + c1, dt);
            vcb = ldany(Wap, rowoff + c1, dt) + ldany(Wbp, rowoff + c1, dt);
        }
        wp1[i] = packh2(v1a * m0, v1b * m1);
        wp2[i] = packh2(v2a * m0, v2b * m1);
        wpc[i] = packh2(vca * m0, vcb * m1);
    }

    const float bias1 = ldany(B1p, u, dt);
    const float bias2 = ldany(B2p, u, dt);
    const float biasc = ldany(Bap, u, dt) + ldany(Bbp, u, dt);
    float hcur = ldany(h0p, (size_t)b * 256 + unit, dt);

    // write slots (in the WRITE buffer): state slot ws0, next-layer-input ws1
    int ws0, ws1;
    if (lay == 0)      { ws0 = 64 + u;             ws1 = ZROW + u; }
    else if (lay == 1) { ws0 = ZROW + 77 + u;      ws1 = 2 * ZROW + u; }
    else               { ws0 = 2 * ZROW + 51 + u;  ws1 = 2 * ZROW + 51 + u; }

    const int zoff = zbase + 2 * pbase;  // float offset of lane's z slice (16B-aligned)

    __shared__ float zs[2 * ZBUF];
    for (int i = tid; i < 2 * ZBUF; i += 1024) zs[i] = 0.f;
    __syncthreads();

    if (part == 0) { zs[ws0] = hcur; zs[ZBUF + ws0] = hcur; }  // h_init in both buffers

    // x staging duty: 32 lanes (tid 512..543), 2 floats each -> z0.x[0..64).
    // buf0.x = x(0); regs carry x(1).
    const bool isx = (tid >= 512) && (tid < 544);
    const int  xj  = tid - 512;
    const size_t xbase = (size_t)b * T_ * F_;
    const size_t obase = (size_t)b * T_ * H2_;
    float xf0 = 0.f, xf1 = 0.f;
    if (isx) {
        zs[2 * xj]     = ldany(xp, xbase + 2 * xj, dt);
        zs[2 * xj + 1] = ldany(xp, xbase + 2 * xj + 1, dt);
        xf0 = ldany(xp, xbase + F_ + 2 * xj, dt);
        xf1 = ldany(xp, xbase + F_ + 2 * xj + 1, dt);
    }
    __syncthreads();

    for (int s = 0; s < T_ + 2; ++s) {
        const int pr = s & 1;
        const float* rb = &zs[pr * ZBUF];
        float* wb = &zs[(pr ^ 1) * ZBUF];

        float a1 = 0.f, a2 = 0.f, ac = 0.f;   // bias added AFTER reduction
        const float4* zv = (const float4*)(rb + zoff);
#pragma unroll
        for (int i = 0; i < NPL4 / 2; ++i) {
            float4 q = zv[i];
            half2_t pa1 = u2h(wp1[2 * i]), pb1 = u2h(wp1[2 * i + 1]);
            half2_t pa2 = u2h(wp2[2 * i]), pb2 = u2h(wp2[2 * i + 1]);
            half2_t pac = u2h(wpc[2 * i]), pbc = u2h(wpc[2 * i + 1]);
            a1 = fmaf((float)pa1.x, q.x, a1); a1 = fmaf((float)pa1.y, q.y, a1);
            a2 = fmaf((float)pa2.x, q.x, a2); a2 = fmaf((float)pa2.y, q.y, a2);
            ac = fmaf((float)pac.x, q.x, ac); ac = fmaf((float)pac.y, q.y, ac);
            a1 = fmaf((float)pb1.x, q.z, a1); a1 = fmaf((float)pb1.y, q.w, a1);
            a2 = fmaf((float)pb2.x, q.z, a2); a2 = fmaf((float)pb2.y, q.w, a2);
            ac = fmaf((float)pbc.x, q.z, ac); ac = fmaf((float)pbc.y, q.w, ac);
        }
        a1 = quad_reduce(a1);
        a2 = quad_reduce(a2);
        ac = quad_reduce(ac);

        // x pipeline: regs hold x(s+1) -> write into wb (read next tick);
        // then prefetch x(s+2) (full tick of latency to hide).
        if (isx && s + 1 < T_) {
            wb[2 * xj] = xf0; wb[2 * xj + 1] = xf1;
            if (s + 2 < T_) {
                size_t xi = xbase + (size_t)(s + 2) * F_ + 2 * xj;
                xf0 = ldany(xp, xi, dt);
                xf1 = ldany(xp, xi + 1, dt);
            }
        }

        if (part == 0 && s >= smin && s <= smax) {
            float ff1 = tanh_f(bias1 + a1), ff2 = tanh_f(bias2 + a2), ti = sigm_f(biasc + ac);
            float hn = ff1 + ti * (ff2 - ff1);
            wb[ws0] = hn; wb[ws1] = hn;
            hcur = hn;
            if (lay == 2) stout(outp, obase + (size_t)(s - 2) * H2_ + u, hn, dt);
        }
        __syncthreads();
    }

    // final hidden state hx = [L0 | L1 | L2] == unit order
    if (part == 0)
        stout(outp, (size_t)B_ * T_ * H2_ + (size_t)b * 256 + unit, hcur, dt);
}

extern "C" void kernel_launch(void* const* d_in, const int* in_sizes, int n_in,
                              void* d_out, int out_size, void* d_ws, size_t ws_size,
                              hipStream_t stream) {
    (void)in_sizes; (void)out_size; (void)d_ws; (void)ws_size;
    Params p;
    const int m = (n_in < 29) ? n_in : 29;
    for (int i = 0; i < m; ++i) p.in[i] = d_in[i];
    liquid_cfc_kernel<<<dim3(B_), dim3(1024), 0, stream>>>(p, d_out);
}

// Round 6
// 22503.833 us; speedup vs baseline: 1.1231x; 1.1231x over previous
//
#include <hip/hip_runtime.h>
#include <stdint.h>

#define B_   128
#define T_   4096
#define F_   64
#define H0_  77
#define H1_  51
#define H2_  128
#define K0_  141
#define K1_  128
#define K2_  179
// Each unit's dot product is split across 2 lanes. Per-lane pair count is a
// uniform compile-time 46 (covers L2's half-share of ceil(179/2)=90 pairs);
// per-layer half-split bases are EVEN (36/32/46) so every lane's z pointer is
// 16B-aligned -> explicit float4 LDS loads.
#define NPL  46
#define ZROW 192           // floats per z row (zero-padded)
#define ZBUF 576           // floats per z buffer (3 rows); double-buffered

typedef _Float16 half2_t __attribute__((ext_vector_type(2)));

__device__ inline float bf2f(unsigned short v) {
    unsigned u = ((unsigned)v) << 16;
    return __builtin_bit_cast(float, u);
}
__device__ inline unsigned short f2bf(float f) {
    unsigned u = __builtin_bit_cast(unsigned, f);
    unsigned r = (u + 0x7FFFu + ((u >> 16) & 1u)) >> 16;   // RNE, finite values
    return (unsigned short)r;
}
__device__ inline uint32_t packh2(float a, float b) {
    half2_t h; h.x = (_Float16)a; h.y = (_Float16)b;
    return __builtin_bit_cast(uint32_t, h);
}
__device__ inline half2_t u2h(uint32_t u) { return __builtin_bit_cast(half2_t, u); }

// dt: 0 = fp32, 1 = bf16, 2 = fp16
__device__ inline float ldany(const void* p, size_t i, int dt) {
    if (dt == 0) return ((const float*)p)[i];
    if (dt == 1) return bf2f(((const unsigned short*)p)[i]);
    return (float)((const _Float16*)p)[i];
}
__device__ inline void stout(void* p, size_t i, float v, int dt) {
    if (dt == 0)      ((float*)p)[i] = v;
    else if (dt == 1) ((unsigned short*)p)[i] = f2bf(v);
    else              ((_Float16*)p)[i] = (_Float16)v;
}

__device__ inline float sigm_f(float x) { return 1.0f / (1.0f + __expf(-x)); }
__device__ inline float tanh_f(float x) { return 2.0f / (1.0f + __expf(-2.0f * x)) - 1.0f; }

// quad-perm DPP add with lane^1 partner (pure VALU; no ds_bpermute).
// 0xB1 = quad_perm(1,0,3,2) -> lane^1
template <int CTRL>
__device__ inline float dpp_add(float x) {
    int v = __builtin_amdgcn_update_dpp(0, __builtin_bit_cast(int, x),
                                        CTRL, 0xF, 0xF, true);
    return x + __builtin_bit_cast(float, v);
}

struct Params { const void* in[29]; };

// 512 threads: unit = tid>>1 (0..255 = [L0|L1|L2] state order), half = tid&1.
// Software pipeline: tick s computes L0:h0, L1:h1 (1 step behind), L2:h2 (2
// behind) in parallel; z block double-buffered (read buf[s&1], write
// buf[s&1^1]); ONE barrier per tick. Bias added ONCE after the pair reduce.
//
// __launch_bounds__(512, 1): 1 block/CU -> 8 waves/CU -> 2 waves/SIMD ->
// 256-VGPR budget. Measured: (512,2) gave only 128 regs (second arg behaves
// as CUDA min-blocks/CU) -> the 138 packed-weight dwords spilled; (512,1)
// makes them truly register-resident.
__global__ __launch_bounds__(512, 1)
void liquid_cfc_kernel(Params p, void* __restrict__ outp) {
    const int tid  = threadIdx.x;
    const int b    = blockIdx.x;
    const int unit = tid >> 1;
    const int half = tid & 1;

    int lay, u, k, nph, zbase, smin;
    if (unit < H0_)              { lay = 0; u = unit;        k = K0_; nph = 36;  zbase = 0;        smin = 0; }
    else if (unit < H0_ + H1_)   { lay = 1; u = unit - H0_;  k = K1_; nph = 32;  zbase = ZROW;     smin = 1; }
    else                         { lay = 2; u = unit - 128;  k = K2_; nph = NPL; zbase = 2 * ZROW; smin = 2; }
    const int smax = smin + T_ - 1;

    const void* xp  = p.in[0];
    const void* h0p = p.in[1];
    // dict order per layer: m, W1, W2, Wa, Wb, b1, b2, ba, bb
    const void* Mp  = p.in[2 + 9 * lay + 0];
    const void* W1p = p.in[2 + 9 * lay + 1];
    const void* W2p = p.in[2 + 9 * lay + 2];
    const void* Wap = p.in[2 + 9 * lay + 3];
    const void* Wbp = p.in[2 + 9 * lay + 4];
    const void* B1p = p.in[2 + 9 * lay + 5];
    const void* B2p = p.in[2 + 9 * lay + 6];
    const void* Bap = p.in[2 + 9 * lay + 7];
    const void* Bbp = p.in[2 + 9 * lay + 8];

    // dtype probe on mask m_0 (values exactly 0.0/1.0)
    int dt;
    {
        const unsigned short* q = (const unsigned short*)p.in[2];
        bool anyf16 = false, lowNZ = false;
        for (int i = 0; i < 64; ++i) {
            unsigned short v = q[i];
            if (v == 0x3C00) anyf16 = true;
            if ((i & 1) == 0 && v != 0) lowNZ = true;
        }
        dt = anyf16 ? 2 : (lowNZ ? 1 : 0);
    }

    // one-time: load + mask + fold (Wa+Wb); this lane holds pairs
    // [half*nph, half*nph+NPL) of its unit's row (zero-padded).
    // 3 x 46 u32 = 138 VGPRs, register-resident under the 256-reg budget.
    const int rowoff = u * k;
    const int pb = half * nph;
    uint32_t wp1[NPL], wp2[NPL], wpc[NPL];
#pragma unroll
    for (int i = 0; i < NPL; ++i) {
        const int c0 = 2 * (pb + i), c1 = c0 + 1;
        const bool v0 = (i < nph) && (c0 < k);
        const bool v1 = (i < nph) && (c1 < k);
        float m0 = 0.f, m1 = 0.f, v1a = 0.f, v1b = 0.f, v2a = 0.f, v2b = 0.f,
              vca = 0.f, vcb = 0.f;
        if (v0) {
            m0  = ldany(Mp,  rowoff + c0, dt);
            v1a = ldany(W1p, rowoff + c0, dt);
            v2a = ldany(W2p, rowoff + c0, dt);
            vca = ldany(Wap, rowoff + c0, dt) + ldany(Wbp, rowoff + c0, dt);
        }
        if (v1) {
            m1  = ldany(Mp,  rowoff + c1, dt);
            v1b = ldany(W1p, rowoff + c1, dt);
            v2b = ldany(W2p, rowoff + c1, dt);
            vcb = ldany(Wap, rowoff + c1, dt) + ldany(Wbp, rowoff + c1, dt);
        }
        wp1[i] = packh2(v1a * m0, v1b * m1);
        wp2[i] = packh2(v2a * m0, v2b * m1);
        wpc[i] = packh2(vca * m0, vcb * m1);
    }

    const float bias1 = ldany(B1p, u, dt);
    const float bias2 = ldany(B2p, u, dt);
    const float biasc = ldany(Bap, u, dt) + ldany(Bbp, u, dt);
    float hcur = ldany(h0p, (size_t)b * 256 + unit, dt);

    // write slots (in the WRITE buffer): state slot ws0, next-layer-input ws1
    int ws0, ws1;
    if (lay == 0)      { ws0 = 64 + u;             ws1 = ZROW + u; }
    else if (lay == 1) { ws0 = ZROW + 77 + u;      ws1 = 2 * ZROW + u; }
    else               { ws0 = 2 * ZROW + 51 + u;  ws1 = 2 * ZROW + 51 + u; }

    const int zoff = zbase + 2 * pb;   // float offset of this lane's z slice (16B-aligned)

    __shared__ float zs[2 * ZBUF];
    for (int i = tid; i < 2 * ZBUF; i += 512) zs[i] = 0.f;
    __syncthreads();

    if (half == 0) { zs[ws0] = hcur; zs[ZBUF + ws0] = hcur; }  // h_init in both buffers

    // x staging duty: 32 lanes (tid 256..287), 2 floats each -> z0.x[0..64).
    // buf0.x = x(0); regs carry x(1).
    const bool isx = (tid >= 256) && (tid < 288);
    const int  xj  = tid - 256;
    const size_t xbase = (size_t)b * T_ * F_;
    const size_t obase = (size_t)b * T_ * H2_;
    float xf0 = 0.f, xf1 = 0.f;
    if (isx) {
        zs[2 * xj]     = ldany(xp, xbase + 2 * xj, dt);
        zs[2 * xj + 1] = ldany(xp, xbase + 2 * xj + 1, dt);
        xf0 = ldany(xp, xbase + F_ + 2 * xj, dt);
        xf1 = ldany(xp, xbase + F_ + 2 * xj + 1, dt);
    }
    __syncthreads();

    for (int s = 0; s < T_ + 2; ++s) {
        const int pr = s & 1;
        const float* rb = &zs[pr * ZBUF];
        float* wb = &zs[(pr ^ 1) * ZBUF];

        // x pipeline AT TICK TOP: write x(s+1) (held in regs) into wb, then
        // ISSUE the x(s+2) load. The load completes under the dot below, so
        // the compiler's vmcnt(0) drain before s_barrier costs ~nothing
        // (previously it exposed ~900cy of HBM latency every tick).
        if (isx) {
            if (s + 1 < T_) { wb[2 * xj] = xf0; wb[2 * xj + 1] = xf1; }
            if (s + 2 < T_) {
                size_t xi = xbase + (size_t)(s + 2) * F_ + 2 * xj;
                xf0 = ldany(xp, xi, dt);
                xf1 = ldany(xp, xi + 1, dt);
            }
        }

        float a1 = 0.f, a2 = 0.f, ac = 0.f;   // bias added AFTER reduction
        const float4* zv = (const float4*)(rb + zoff);
#pragma unroll
        for (int i = 0; i < NPL / 2; ++i) {
            float4 q = zv[i];
            half2_t pa1 = u2h(wp1[2 * i]), pb1 = u2h(wp1[2 * i + 1]);
            half2_t pa2 = u2h(wp2[2 * i]), pb2 = u2h(wp2[2 * i + 1]);
            half2_t pac = u2h(wpc[2 * i]), pbc = u2h(wpc[2 * i + 1]);
            a1 = fmaf((float)pa1.x, q.x, a1); a1 = fmaf((float)pa1.y, q.y, a1);
            a2 = fmaf((float)pa2.x, q.x, a2); a2 = fmaf((float)pa2.y, q.y, a2);
            ac = fmaf((float)pac.x, q.x, ac); ac = fmaf((float)pac.y, q.y, ac);
            a1 = fmaf((float)pb1.x, q.z, a1); a1 = fmaf((float)pb1.y, q.w, a1);
            a2 = fmaf((float)pb2.x, q.z, a2); a2 = fmaf((float)pb2.y, q.w, a2);
            ac = fmaf((float)pbc.x, q.z, ac); ac = fmaf((float)pbc.y, q.w, ac);
        }
        // partner (lane^1) reduce via DPP quad_perm — pure VALU, no LDS pipe
        a1 = dpp_add<0xB1>(a1);
        a2 = dpp_add<0xB1>(a2);
        ac = dpp_add<0xB1>(ac);

        if (half == 0 && s >= smin && s <= smax) {
            float ff1 = tanh_f(bias1 + a1), ff2 = tanh_f(bias2 + a2), ti = sigm_f(biasc + ac);
            float hn = ff1 + ti * (ff2 - ff1);
            wb[ws0] = hn; wb[ws1] = hn;
            hcur = hn;
            if (lay == 2) stout(outp, obase + (size_t)(s - 2) * H2_ + u, hn, dt);
        }
        __syncthreads();
    }

    // final hidden state hx = [L0 | L1 | L2] == unit order
    if (half == 0)
        stout(outp, (size_t)B_ * T_ * H2_ + (size_t)b * 256 + unit, hcur, dt);
}

extern "C" void kernel_launch(void* const* d_in, const int* in_sizes, int n_in,
                              void* d_out, int out_size, void* d_ws, size_t ws_size,
                              hipStream_t stream) {
    (void)in_sizes; (void)out_size; (void)d_ws; (void)ws_size;
    Params p;
    const int m = (n_in < 29) ? n_in : 29;
    for (int i = 0; i < m; ++i) p.in[i] = d_in[i];
    liquid_cfc_kernel<<<dim3(B_), dim3(512), 0, stream>>>(p, d_out);
}

// Round 7
// 6778.666 us; speedup vs baseline: 3.7284x; 3.3198x over previous
//
#include <hip/hip_runtime.h>
#include <stdint.h>

#define B_   128
#define T_   4096
#define F_   64
#define H0_  77
#define H1_  51
#define H2_  128
#define K0_  141
#define K1_  128
#define K2_  179
// Each unit's dot product is split across 2 lanes; per-lane weight slice is
// padded to 48 pairs (12 float4 groups). W1/W2 packed-fp16 pairs live in
// VGPRs (96 dwords -> fits the measured 128-reg cap for 512-thread blocks);
// the folded (Wa+Wb) matrix lives in LDS, index-major [12][512] float4 so
// per-tick reads are lane-consecutive ds_read_b128 (conflict-free, pipelined
// -- unlike the serialized scratch reloads the spill was costing us).
#define NPG  12            // float4 groups per lane (48 pairs)
#define ZROW 192           // floats per z row (zero-padded)
#define ZBUF 576           // floats per z buffer (3 rows); double-buffered

typedef _Float16 half2_t __attribute__((ext_vector_type(2)));

__device__ inline float bf2f(unsigned short v) {
    unsigned u = ((unsigned)v) << 16;
    return __builtin_bit_cast(float, u);
}
__device__ inline unsigned short f2bf(float f) {
    unsigned u = __builtin_bit_cast(unsigned, f);
    unsigned r = (u + 0x7FFFu + ((u >> 16) & 1u)) >> 16;   // RNE, finite values
    return (unsigned short)r;
}
__device__ inline uint32_t packh2(float a, float b) {
    half2_t h; h.x = (_Float16)a; h.y = (_Float16)b;
    return __builtin_bit_cast(uint32_t, h);
}
__device__ inline half2_t u2h(uint32_t u) { return __builtin_bit_cast(half2_t, u); }
__device__ inline half2_t f2h(float f) {
    return __builtin_bit_cast(half2_t, __builtin_bit_cast(uint32_t, f));
}

// dt: 0 = fp32, 1 = bf16, 2 = fp16
__device__ inline float ldany(const void* p, size_t i, int dt) {
    if (dt == 0) return ((const float*)p)[i];
    if (dt == 1) return bf2f(((const unsigned short*)p)[i]);
    return (float)((const _Float16*)p)[i];
}
__device__ inline void stout(void* p, size_t i, float v, int dt) {
    if (dt == 0)      ((float*)p)[i] = v;
    else if (dt == 1) ((unsigned short*)p)[i] = f2bf(v);
    else              ((_Float16*)p)[i] = (_Float16)v;
}

__device__ inline float sigm_f(float x) { return 1.0f / (1.0f + __expf(-x)); }
__device__ inline float tanh_f(float x) { return 2.0f / (1.0f + __expf(-2.0f * x)) - 1.0f; }

// quad-perm DPP add with lane^1 partner (pure VALU; no ds_bpermute).
template <int CTRL>
__device__ inline float dpp_add(float x) {
    int v = __builtin_amdgcn_update_dpp(0, __builtin_bit_cast(int, x),
                                        CTRL, 0xF, 0xF, true);
    return x + __builtin_bit_cast(float, v);
}

struct Params { const void* in[29]; };

// 512 threads: unit = tid>>1 (0..255 = [L0|L1|L2] state order), half = tid&1.
// Software pipeline: tick s computes L0:h0, L1:h1 (1 behind), L2:h2 (2
// behind) in parallel; z block double-buffered; ONE barrier per tick.
// Bias added ONCE after the pair reduce.
__global__ __launch_bounds__(512)
__attribute__((amdgpu_waves_per_eu(2, 8)))
void liquid_cfc_kernel(Params p, void* __restrict__ outp) {
    const int tid  = threadIdx.x;
    const int b    = blockIdx.x;
    const int unit = tid >> 1;
    const int half = tid & 1;

    int lay, u, k, nph, zbase, smin;
    if (unit < H0_)              { lay = 0; u = unit;        k = K0_; nph = 36; zbase = 0;        smin = 0; }
    else if (unit < H0_ + H1_)   { lay = 1; u = unit - H0_;  k = K1_; nph = 32; zbase = ZROW;     smin = 1; }
    else                         { lay = 2; u = unit - 128;  k = K2_; nph = 46; zbase = 2 * ZROW; smin = 2; }
    const int smax = smin + T_ - 1;

    const void* xp  = p.in[0];
    const void* h0p = p.in[1];
    // dict order per layer: m, W1, W2, Wa, Wb, b1, b2, ba, bb
    const void* Mp  = p.in[2 + 9 * lay + 0];
    const void* W1p = p.in[2 + 9 * lay + 1];
    const void* W2p = p.in[2 + 9 * lay + 2];
    const void* Wap = p.in[2 + 9 * lay + 3];
    const void* Wbp = p.in[2 + 9 * lay + 4];
    const void* B1p = p.in[2 + 9 * lay + 5];
    const void* B2p = p.in[2 + 9 * lay + 6];
    const void* Bap = p.in[2 + 9 * lay + 7];
    const void* Bbp = p.in[2 + 9 * lay + 8];

    // dtype probe on mask m_0 (values exactly 0.0/1.0)
    int dt;
    {
        const unsigned short* q = (const unsigned short*)p.in[2];
        bool anyf16 = false, lowNZ = false;
        for (int i = 0; i < 64; ++i) {
            unsigned short v = q[i];
            if (v == 0x3C00) anyf16 = true;
            if ((i & 1) == 0 && v != 0) lowNZ = true;
        }
        dt = anyf16 ? 2 : (lowNZ ? 1 : 0);
    }

    __shared__ float  zs[2 * ZBUF];
    __shared__ float4 wpcl[NPG * 512];   // folded (Wa+Wb), index-major

    // one-time: load + mask + fold (Wa+Wb). This lane holds pairs
    // [half*nph, half*nph+48) of its unit's row (zero-padded).
    // wp1/wp2 (96 dwords) -> registers; wpc -> LDS.
    const int rowoff = u * k;
    const int pb = half * nph;
    uint32_t wp1[4 * NPG], wp2[4 * NPG];
#pragma unroll
    for (int i4 = 0; i4 < NPG; ++i4) {
        uint32_t cw[4];
#pragma unroll
        for (int r = 0; r < 4; ++r) {
            const int i = 4 * i4 + r;
            const int c0 = 2 * (pb + i), c1 = c0 + 1;
            const bool v0 = (i < nph) && (c0 < k);
            const bool v1 = (i < nph) && (c1 < k);
            float m0 = 0.f, m1 = 0.f, v1a = 0.f, v1b = 0.f, v2a = 0.f,
                  v2b = 0.f, vca = 0.f, vcb = 0.f;
            if (v0) {
                m0  = ldany(Mp,  rowoff + c0, dt);
                v1a = ldany(W1p, rowoff + c0, dt);
                v2a = ldany(W2p, rowoff + c0, dt);
                vca = ldany(Wap, rowoff + c0, dt) + ldany(Wbp, rowoff + c0, dt);
            }
            if (v1) {
                m1  = ldany(Mp,  rowoff + c1, dt);
                v1b = ldany(W1p, rowoff + c1, dt);
                v2b = ldany(W2p, rowoff + c1, dt);
                vcb = ldany(Wap, rowoff + c1, dt) + ldany(Wbp, rowoff + c1, dt);
            }
            wp1[i] = packh2(v1a * m0, v1b * m1);
            wp2[i] = packh2(v2a * m0, v2b * m1);
            cw[r]  = packh2(vca * m0, vcb * m1);
        }
        float4 cv;
        cv.x = __builtin_bit_cast(float, cw[0]);
        cv.y = __builtin_bit_cast(float, cw[1]);
        cv.z = __builtin_bit_cast(float, cw[2]);
        cv.w = __builtin_bit_cast(float, cw[3]);
        wpcl[i4 * 512 + tid] = cv;   // lane-consecutive 16B -> conflict-free
    }

    const float bias1 = ldany(B1p, u, dt);
    const float bias2 = ldany(B2p, u, dt);
    const float biasc = ldany(Bap, u, dt) + ldany(Bbp, u, dt);
    float hcur = ldany(h0p, (size_t)b * 256 + unit, dt);

    // write slots (in the WRITE buffer): state slot ws0, next-layer-input ws1
    int ws0, ws1;
    if (lay == 0)      { ws0 = 64 + u;             ws1 = ZROW + u; }
    else if (lay == 1) { ws0 = ZROW + 77 + u;      ws1 = 2 * ZROW + u; }
    else               { ws0 = 2 * ZROW + 51 + u;  ws1 = 2 * ZROW + 51 + u; }

    const int zoff = zbase + 2 * pb;   // float offset of lane's z slice (16B-aligned)

    for (int i = tid; i < 2 * ZBUF; i += 512) zs[i] = 0.f;
    __syncthreads();

    if (half == 0) { zs[ws0] = hcur; zs[ZBUF + ws0] = hcur; }  // h_init in both buffers

    // x staging duty: 32 lanes on tid 160..191 (L1 lanes: shortest dot, no
    // per-tick global stores -> lightest wave carries the x-load latency).
    // buf0.x = x(0); regs carry x(1).
    const bool isx = (tid >= 160) && (tid < 192);
    const int  xj  = tid - 160;
    const size_t xbase = (size_t)b * T_ * F_;
    const size_t obase = (size_t)b * T_ * H2_;
    float xf0 = 0.f, xf1 = 0.f;
    if (isx) {
        zs[2 * xj]     = ldany(xp, xbase + 2 * xj, dt);
        zs[2 * xj + 1] = ldany(xp, xbase + 2 * xj + 1, dt);
        xf0 = ldany(xp, xbase + F_ + 2 * xj, dt);
        xf1 = ldany(xp, xbase + F_ + 2 * xj + 1, dt);
    }
    __syncthreads();

    for (int s = 0; s < T_ + 2; ++s) {
        const int pr = s & 1;
        const float* rb = &zs[pr * ZBUF];
        float* wb = &zs[(pr ^ 1) * ZBUF];

        // x pipeline AT TICK TOP: write x(s+1) (in regs) into wb, then issue
        // the x(s+2) load so it completes under the dot below.
        if (isx) {
            if (s + 1 < T_) { wb[2 * xj] = xf0; wb[2 * xj + 1] = xf1; }
            if (s + 2 < T_) {
                size_t xi = xbase + (size_t)(s + 2) * F_ + 2 * xj;
                xf0 = ldany(xp, xi, dt);
                xf1 = ldany(xp, xi + 1, dt);
            }
        }

        float a1 = 0.f, a2 = 0.f, ac = 0.f;   // bias added AFTER reduction
        const float4* zv = (const float4*)(rb + zoff);
#pragma unroll
        for (int i4 = 0; i4 < NPG; ++i4) {
            float4 q0 = zv[2 * i4];
            float4 q1 = zv[2 * i4 + 1];
            float4 cv = wpcl[i4 * 512 + tid];
            half2_t w10 = u2h(wp1[4 * i4 + 0]), w11 = u2h(wp1[4 * i4 + 1]);
            half2_t w12 = u2h(wp1[4 * i4 + 2]), w13 = u2h(wp1[4 * i4 + 3]);
            half2_t w20 = u2h(wp2[4 * i4 + 0]), w21 = u2h(wp2[4 * i4 + 1]);
            half2_t w22 = u2h(wp2[4 * i4 + 2]), w23 = u2h(wp2[4 * i4 + 3]);
            half2_t c0 = f2h(cv.x), c1 = f2h(cv.y), c2 = f2h(cv.z), c3 = f2h(cv.w);
            a1 = fmaf((float)w10.x, q0.x, a1); a1 = fmaf((float)w10.y, q0.y, a1);
            a1 = fmaf((float)w11.x, q0.z, a1); a1 = fmaf((float)w11.y, q0.w, a1);
            a1 = fmaf((float)w12.x, q1.x, a1); a1 = fmaf((float)w12.y, q1.y, a1);
            a1 = fmaf((float)w13.x, q1.z, a1); a1 = fmaf((float)w13.y, q1.w, a1);
            a2 = fmaf((float)w20.x, q0.x, a2); a2 = fmaf((float)w20.y, q0.y, a2);
            a2 = fmaf((float)w21.x, q0.z, a2); a2 = fmaf((float)w21.y, q0.w, a2);
            a2 = fmaf((float)w22.x, q1.x, a2); a2 = fmaf((float)w22.y, q1.y, a2);
            a2 = fmaf((float)w23.x, q1.z, a2); a2 = fmaf((float)w23.y, q1.w, a2);
            ac = fmaf((float)c0.x, q0.x, ac);  ac = fmaf((float)c0.y, q0.y, ac);
            ac = fmaf((float)c1.x, q0.z, ac);  ac = fmaf((float)c1.y, q0.w, ac);
            ac = fmaf((float)c2.x, q1.x, ac);  ac = fmaf((float)c2.y, q1.y, ac);
            ac = fmaf((float)c3.x, q1.z, ac);  ac = fmaf((float)c3.y, q1.w, ac);
        }
        // partner (lane^1) reduce via DPP quad_perm — pure VALU, no LDS pipe
        a1 = dpp_add<0xB1>(a1);
        a2 = dpp_add<0xB1>(a2);
        ac = dpp_add<0xB1>(ac);

        if (half == 0 && s >= smin && s <= smax) {
            float ff1 = tanh_f(bias1 + a1), ff2 = tanh_f(bias2 + a2), ti = sigm_f(biasc + ac);
            float hn = ff1 + ti * (ff2 - ff1);
            wb[ws0] = hn; wb[ws1] = hn;
            hcur = hn;
            if (lay == 2) stout(outp, obase + (size_t)(s - 2) * H2_ + u, hn, dt);
        }
        __syncthreads();
    }

    // final hidden state hx = [L0 | L1 | L2] == unit order
    if (half == 0)
        stout(outp, (size_t)B_ * T_ * H2_ + (size_t)b * 256 + unit, hcur, dt);
}

extern "C" void kernel_launch(void* const* d_in, const int* in_sizes, int n_in,
                              void* d_out, int out_size, void* d_ws, size_t ws_size,
                              hipStream_t stream) {
    (void)in_sizes; (void)out_size; (void)d_ws; (void)ws_size;
    Params p;
    const int m = (n_in < 29) ? n_in : 29;
    for (int i = 0; i < m; ++i) p.in[i] = d_in[i];
    liquid_cfc_kernel<<<dim3(B_), dim3(512), 0, stream>>>(p, d_out);
}